// Round 1
// 3312.719 us; speedup vs baseline: 1.3305x; 1.3305x over previous
//
#include <hip/hip_runtime.h>
#include <math.h>

#define B 2048
#define H 256
#define INDIM 320
#define NOPS 1883
#define STEPS 20

typedef _Float16 f16;
typedef _Float16 f16x4 __attribute__((ext_vector_type(4)));
typedef _Float16 f16x8 __attribute__((ext_vector_type(8)));
typedef float f32x4 __attribute__((ext_vector_type(4)));

// XOR swizzle: 4 16B-slots per 64B row; spread rows r, r+4 across banks too.
#define SWZ(r, s) ((s) ^ ((r) & 3) ^ (((r) >> 2) & 1))

// ---------------- init: x = concat(geo, sem); h0a = h1a = 0 ----------------
__global__ __launch_bounds__(256) void init_kernel(const float* __restrict__ geo,
                                                   const float* __restrict__ sem,
                                                   float* __restrict__ x,
                                                   float* __restrict__ h0,
                                                   float* __restrict__ h1) {
    int i = blockIdx.x * blockDim.x + threadIdx.x;
    if (i < B * INDIM) {
        int b = i / INDIM, c = i % INDIM;
        x[i] = (c < 256) ? geo[b * 256 + c] : sem[b * 64 + (c - 256)];
    }
    if (i < B * H) { h0[i] = 0.0f; h1[i] = 0.0f; }
}

// ---------------- generic tiled GEMM (used only for opp precompute) ----------------
#define BM 64
#define BN 64
#define BK 16
__global__ __launch_bounds__(256) void gemm_tn(const float* __restrict__ A,
                                               const float* __restrict__ Bm,
                                               const float* __restrict__ bias,
                                               float* __restrict__ C,
                                               int M, int N, int K) {
    __shared__ float As[BK][BM];
    __shared__ float Bs[BK][BN];
    int tid = threadIdx.x;
    int bm0 = blockIdx.y * BM;
    int bn0 = blockIdx.x * BN;
    int tx = tid & 15, ty = tid >> 4;
    int lr = tid >> 2;
    int lk = (tid & 3) << 2;

    float acc[4][4];
#pragma unroll
    for (int i = 0; i < 4; ++i)
#pragma unroll
        for (int j = 0; j < 4; ++j) acc[i][j] = 0.0f;

    for (int k0 = 0; k0 < K; k0 += BK) {
        {
            int gr = bm0 + lr;
            float4 v = make_float4(0.f, 0.f, 0.f, 0.f);
            if (gr < M) v = *(const float4*)(A + (size_t)gr * K + k0 + lk);
            As[lk + 0][lr] = v.x; As[lk + 1][lr] = v.y;
            As[lk + 2][lr] = v.z; As[lk + 3][lr] = v.w;
        }
        {
            int gn = bn0 + lr;
            float4 v = make_float4(0.f, 0.f, 0.f, 0.f);
            if (gn < N) v = *(const float4*)(Bm + (size_t)gn * K + k0 + lk);
            Bs[lk + 0][lr] = v.x; Bs[lk + 1][lr] = v.y;
            Bs[lk + 2][lr] = v.z; Bs[lk + 3][lr] = v.w;
        }
        __syncthreads();
#pragma unroll
        for (int k = 0; k < BK; ++k) {
            float a[4], b[4];
#pragma unroll
            for (int i = 0; i < 4; ++i) a[i] = As[k][ty * 4 + i];
#pragma unroll
            for (int j = 0; j < 4; ++j) b[j] = Bs[k][tx * 4 + j];
#pragma unroll
            for (int i = 0; i < 4; ++i)
#pragma unroll
                for (int j = 0; j < 4; ++j) acc[i][j] = fmaf(a[i], b[j], acc[i][j]);
        }
        __syncthreads();
    }
#pragma unroll
    for (int i = 0; i < 4; ++i) {
        int gr = bm0 + ty * 4 + i;
        if (gr >= M) continue;
#pragma unroll
        for (int j = 0; j < 4; ++j) {
            int gc = bn0 + tx * 4 + j;
            if (gc < N) C[(size_t)gr * N + gc] = acc[i][j] + (bias ? bias[gc] : 0.0f);
        }
    }
}

// ---------------- fp32 -> fp16 hi/lo split (lo pre-scaled x1024) + row sumsq ----------
// one wave per 256-col row; grid = ceil(rows/4), 256 threads.
__global__ __launch_bounds__(256) void cvt_rows(const float* __restrict__ A, int rows,
                                                f16* __restrict__ hi, f16* __restrict__ lo,
                                                float* __restrict__ sq) {
    int row = blockIdx.x * 4 + (threadIdx.x >> 6);
    int lane = threadIdx.x & 63;
    if (row >= rows) return;
    float4 v = *(const float4*)(A + (size_t)row * 256 + lane * 4);
    float vv[4] = {v.x, v.y, v.z, v.w};
    f16x4 h, l;
    float s = 0.0f;
#pragma unroll
    for (int j = 0; j < 4; ++j) {
        float f = vv[j];
        f16 hv = (f16)f;
        float res = f - (float)hv;          // exact
        h[j] = hv;
        l[j] = (f16)(res * 1024.0f);        // keep lo in fp16 normal range
        s = fmaf(f, f, s);
    }
    *(f16x4*)(hi + (size_t)row * 256 + lane * 4) = h;
    *(f16x4*)(lo + (size_t)row * 256 + lane * 4) = l;
    if (sq) {
#pragma unroll
        for (int off = 32; off > 0; off >>= 1) s += __shfl_down(s, off);
        if (lane == 0) sq[row] = s;
    }
}

// ---------------- fused GRU layer (unchanged this round) ----------------
#define GBK 32

__device__ __forceinline__ void gru_gemm_phase(const float* __restrict__ A, int lda,
                                               const float* __restrict__ W, int ldw,
                                               int r0, int c0, int K,
                                               int tid, int tx, int ty,
                                               float acc[3][2][4],
                                               float (*As)[34], float (*Ws)[196]) {
    for (int k0 = 0; k0 < K; k0 += GBK) {
        {
            int row = tid >> 3;
            int kk = (tid & 7) << 2;
            float4 v = *(const float4*)(A + (size_t)(r0 + row) * lda + k0 + kk);
            As[kk + 0][row] = v.x; As[kk + 1][row] = v.y;
            As[kk + 2][row] = v.z; As[kk + 3][row] = v.w;
        }
#pragma unroll
        for (int it = 0; it < 6; ++it) {
            int flat = tid + 256 * it;
            int wrow = flat >> 3;             // 0..191
            int kk = (flat & 7) << 2;
            int g = wrow >> 6, cc = wrow & 63;
            float4 v = *(const float4*)(W + (size_t)((g << 8) + c0 + cc) * ldw + k0 + kk);
            Ws[kk + 0][wrow] = v.x; Ws[kk + 1][wrow] = v.y;
            Ws[kk + 2][wrow] = v.z; Ws[kk + 3][wrow] = v.w;
        }
        __syncthreads();
#pragma unroll
        for (int k = 0; k < GBK; ++k) {
            float a0 = As[k][(ty << 1) + 0];
            float a1 = As[k][(ty << 1) + 1];
#pragma unroll
            for (int g = 0; g < 3; ++g) {
                const float* wp = &Ws[k][g * 64 + (tx << 2)];
                float4 w = *(const float4*)wp;
                acc[g][0][0] = fmaf(a0, w.x, acc[g][0][0]);
                acc[g][0][1] = fmaf(a0, w.y, acc[g][0][1]);
                acc[g][0][2] = fmaf(a0, w.z, acc[g][0][2]);
                acc[g][0][3] = fmaf(a0, w.w, acc[g][0][3]);
                acc[g][1][0] = fmaf(a1, w.x, acc[g][1][0]);
                acc[g][1][1] = fmaf(a1, w.y, acc[g][1][1]);
                acc[g][1][2] = fmaf(a1, w.z, acc[g][1][2]);
                acc[g][1][3] = fmaf(a1, w.w, acc[g][1][3]);
            }
        }
        __syncthreads();
    }
}

__global__ __launch_bounds__(256) void gru_fused(const float* __restrict__ X, int Kx,
                                                 const float* __restrict__ Hprev,
                                                 const float* __restrict__ Wih,
                                                 const float* __restrict__ Whh,
                                                 const float* __restrict__ bih,
                                                 const float* __restrict__ bhh,
                                                 float* __restrict__ Hnew) {
    __shared__ float As[GBK][34];
    __shared__ float Ws[GBK][196];
    int tid = threadIdx.x;
    int c0 = blockIdx.x * 64;
    int r0 = blockIdx.y * 32;
    int tx = tid & 15;
    int ty = tid >> 4;

    float acc_i[3][2][4];
    float acc_h[3][2][4];
#pragma unroll
    for (int g = 0; g < 3; ++g)
#pragma unroll
        for (int i = 0; i < 2; ++i)
#pragma unroll
            for (int j = 0; j < 4; ++j) { acc_i[g][i][j] = 0.0f; acc_h[g][i][j] = 0.0f; }

    gru_gemm_phase(X, Kx, Wih, Kx, r0, c0, Kx, tid, tx, ty, acc_i, As, Ws);
    gru_gemm_phase(Hprev, 256, Whh, 256, r0, c0, 256, tid, tx, ty, acc_h, As, Ws);

    int cbase = c0 + (tx << 2);
    float br[4], bz[4], bn_i[4], bn_h[4];
#pragma unroll
    for (int j = 0; j < 4; ++j) {
        int c = cbase + j;
        br[j]   = bih[c] + bhh[c];
        bz[j]   = bih[256 + c] + bhh[256 + c];
        bn_i[j] = bih[512 + c];
        bn_h[j] = bhh[512 + c];
    }
#pragma unroll
    for (int i = 0; i < 2; ++i) {
        int r = r0 + (ty << 1) + i;
        float4 hv = *(const float4*)(Hprev + (size_t)r * 256 + cbase);
        float hp[4] = {hv.x, hv.y, hv.z, hv.w};
        float o[4];
#pragma unroll
        for (int j = 0; j < 4; ++j) {
            float rg = 1.0f / (1.0f + expf(-(acc_i[0][i][j] + acc_h[0][i][j] + br[j])));
            float zg = 1.0f / (1.0f + expf(-(acc_i[1][i][j] + acc_h[1][i][j] + bz[j])));
            float ng = tanhf(acc_i[2][i][j] + bn_i[j] + rg * (acc_h[2][i][j] + bn_h[j]));
            o[j] = (1.0f - zg) * ng + zg * hp[j];
        }
        *(float4*)(Hnew + (size_t)r * 256 + cbase) = make_float4(o[0], o[1], o[2], o[3]);
    }
}

// ---------------- MFMA split-fp16 scores: logits & -2*h.opp in one pass --------------
// C tile 128(M) x 64(N), 4 waves (2M x 2N), wave tile 64x32 = 4x2 frags of 16x16.
// K chunk = 32 (one mfma k-step). 3-term split: hh -> acc, (h*lo + lo*h) -> acc_x
// with lo pre-scaled 2^10; epilogue folds acc + acc_x * 2^-10.
__global__ __launch_bounds__(256, 2) void scores_mfma(
    const f16* __restrict__ Ahh, const f16* __restrict__ All,
    const f16* __restrict__ W1h, const f16* __restrict__ W1l,
    const f16* __restrict__ W2h, const f16* __restrict__ W2l,
    const float* __restrict__ hsq, const float* __restrict__ be,
    const float* __restrict__ osq, float* __restrict__ out) {
    __shared__ f16 sA[2][128][32];   // [half][m][k], swizzled 16B slots
    __shared__ f16 sB[4][64][32];    // [W1h,W1l,W2h,W2l][n][k]
    int tid = threadIdx.x;
    int lane = tid & 63;
    int wave = tid >> 6;
    int wm = wave >> 1;              // 0..1 -> 64-row half
    int wn = wave & 1;               // 0..1 -> 32-col half
    int n0 = blockIdx.x * 64;
    int m0 = blockIdx.y * 128;

    f32x4 acc1[4][2], acc1x[4][2], acc2[4][2], acc2x[4][2];
#pragma unroll
    for (int i = 0; i < 4; ++i)
#pragma unroll
        for (int j = 0; j < 2; ++j) {
            acc1[i][j] = (f32x4){0.f, 0.f, 0.f, 0.f};
            acc1x[i][j] = (f32x4){0.f, 0.f, 0.f, 0.f};
            acc2[i][j] = (f32x4){0.f, 0.f, 0.f, 0.f};
            acc2x[i][j] = (f32x4){0.f, 0.f, 0.f, 0.f};
        }

    int rB = tid >> 2, slB = tid & 3;
    int gn = n0 + rB;
    bool okB = gn < NOPS;

    for (int k0 = 0; k0 < 256; k0 += 32) {
        // stage A: 2 halves x 128 rows x 4 slots(16B)
#pragma unroll
        for (int it = 0; it < 4; ++it) {
            const f16* src = (it < 2) ? Ahh : All;
            int r = (tid >> 2) + ((it & 1) << 6);      // 0..127
            int slt = tid & 3;
            float4 v = *(const float4*)(src + (size_t)(m0 + r) * 256 + k0 + slt * 8);
            *(float4*)&sA[it >> 1][r][SWZ(r, slt) * 8] = v;
        }
        // stage B: 4 arrays x 64 rows x 4 slots
#pragma unroll
        for (int it = 0; it < 4; ++it) {
            const f16* src = (it == 0) ? W1h : (it == 1) ? W1l : (it == 2) ? W2h : W2l;
            float4 v = make_float4(0.f, 0.f, 0.f, 0.f);
            if (okB) v = *(const float4*)(src + (size_t)gn * 256 + k0 + slB * 8);
            *(float4*)&sB[it][rB][SWZ(rB, slB) * 8] = v;
        }
        __syncthreads();

        f16x8 ah[4], al[4];
#pragma unroll
        for (int fm = 0; fm < 4; ++fm) {
            int r = wm * 64 + fm * 16 + (lane & 15);
            int sl = SWZ(r, lane >> 4);
            ah[fm] = *(const f16x8*)&sA[0][r][sl * 8];
            al[fm] = *(const f16x8*)&sA[1][r][sl * 8];
        }
#pragma unroll
        for (int fn = 0; fn < 2; ++fn) {
            int r = wn * 32 + fn * 16 + (lane & 15);
            int sl = SWZ(r, lane >> 4);
            f16x8 b1h = *(const f16x8*)&sB[0][r][sl * 8];
            f16x8 b1l = *(const f16x8*)&sB[1][r][sl * 8];
            f16x8 b2h = *(const f16x8*)&sB[2][r][sl * 8];
            f16x8 b2l = *(const f16x8*)&sB[3][r][sl * 8];
#pragma unroll
            for (int fm = 0; fm < 4; ++fm) {
                acc1[fm][fn]  = __builtin_amdgcn_mfma_f32_16x16x32_f16(ah[fm], b1h, acc1[fm][fn], 0, 0, 0);
                acc1x[fm][fn] = __builtin_amdgcn_mfma_f32_16x16x32_f16(al[fm], b1h, acc1x[fm][fn], 0, 0, 0);
                acc1x[fm][fn] = __builtin_amdgcn_mfma_f32_16x16x32_f16(ah[fm], b1l, acc1x[fm][fn], 0, 0, 0);
                acc2[fm][fn]  = __builtin_amdgcn_mfma_f32_16x16x32_f16(ah[fm], b2h, acc2[fm][fn], 0, 0, 0);
                acc2x[fm][fn] = __builtin_amdgcn_mfma_f32_16x16x32_f16(al[fm], b2h, acc2x[fm][fn], 0, 0, 0);
                acc2x[fm][fn] = __builtin_amdgcn_mfma_f32_16x16x32_f16(ah[fm], b2l, acc2x[fm][fn], 0, 0, 0);
            }
        }
        __syncthreads();
    }

    const float inv = 1.0f / 1024.0f;
#pragma unroll
    for (int fn = 0; fn < 2; ++fn) {
        int n = n0 + wn * 32 + fn * 16 + (lane & 15);
        if (n >= NOPS) continue;
        float bev = be[n], osv = osq[n];
#pragma unroll
        for (int fm = 0; fm < 4; ++fm) {
#pragma unroll
            for (int r = 0; r < 4; ++r) {
                int m = m0 + wm * 64 + fm * 16 + (lane >> 4) * 4 + r;
                float dot1 = acc1[fm][fn][r] + acc1x[fm][fn][r] * inv;
                float dot2 = acc2[fm][fn][r] + acc2x[fm][fn][r] * inv;
                float logit = dot1 + bev;
                float d2 = hsq[m] + osv - 2.0f * dot2;
                out[(size_t)m * NOPS + n] = logit - 0.5f * sqrtf(fmaxf(d2, 0.0f));
            }
        }
    }
}

// ---------------- per-row argmax (first-index tie-break) ----------------
__global__ __launch_bounds__(256) void argmax_kernel(const float* __restrict__ scores,
                                                     int* __restrict__ sel,
                                                     float* __restrict__ traj) {
    int b = blockIdx.x;
    const float* row = scores + (size_t)b * NOPS;
    float bv = -INFINITY; int bi = 0x7fffffff;
    for (int n = threadIdx.x; n < NOPS; n += 256) {
        float v = row[n];
        if (v > bv) { bv = v; bi = n; }
    }
    __shared__ float sv[256];
    __shared__ int si[256];
    sv[threadIdx.x] = bv; si[threadIdx.x] = bi;
    __syncthreads();
    for (int s = 128; s > 0; s >>= 1) {
        if (threadIdx.x < s) {
            float ov = sv[threadIdx.x + s]; int oi = si[threadIdx.x + s];
            if (ov > sv[threadIdx.x] || (ov == sv[threadIdx.x] && oi < si[threadIdx.x])) {
                sv[threadIdx.x] = ov; si[threadIdx.x] = oi;
            }
        }
        __syncthreads();
    }
    if (threadIdx.x == 0) { sel[b] = si[0]; traj[b] = (float)si[0]; }
}

// ---------------- proj: x = [h_top, op_embeds[sel]] @ Wp(320,512)^T + bp ----------------
__global__ __launch_bounds__(256) void proj_kernel(const float* __restrict__ Hm,
                                                   const float* __restrict__ emb,
                                                   const int* __restrict__ sel,
                                                   const float* __restrict__ Wp,
                                                   const float* __restrict__ bp,
                                                   float* __restrict__ X) {
    __shared__ float As[BK][BM];
    __shared__ float Bs[BK][BN];
    int tid = threadIdx.x;
    int bm0 = blockIdx.y * BM;
    int bn0 = blockIdx.x * BN;
    int tx = tid & 15, ty = tid >> 4;
    int lr = tid >> 2;
    int lk = (tid & 3) << 2;

    float acc[4][4];
#pragma unroll
    for (int i = 0; i < 4; ++i)
#pragma unroll
        for (int j = 0; j < 4; ++j) acc[i][j] = 0.0f;

    for (int k0 = 0; k0 < 512; k0 += BK) {
        {
            int gr = bm0 + lr;
            int kk = k0 + lk;
            const float* src = (kk < 256) ? (Hm + (size_t)gr * 256 + kk)
                                          : (emb + (size_t)sel[gr] * 256 + (kk - 256));
            float4 v = *(const float4*)src;
            As[lk + 0][lr] = v.x; As[lk + 1][lr] = v.y;
            As[lk + 2][lr] = v.z; As[lk + 3][lr] = v.w;
        }
        {
            int gn = bn0 + lr;
            float4 v = *(const float4*)(Wp + (size_t)gn * 512 + k0 + lk);
            Bs[lk + 0][lr] = v.x; Bs[lk + 1][lr] = v.y;
            Bs[lk + 2][lr] = v.z; Bs[lk + 3][lr] = v.w;
        }
        __syncthreads();
#pragma unroll
        for (int k = 0; k < BK; ++k) {
            float a[4], b[4];
#pragma unroll
            for (int i = 0; i < 4; ++i) a[i] = As[k][ty * 4 + i];
#pragma unroll
            for (int j = 0; j < 4; ++j) b[j] = Bs[k][tx * 4 + j];
#pragma unroll
            for (int i = 0; i < 4; ++i)
#pragma unroll
                for (int j = 0; j < 4; ++j) acc[i][j] = fmaf(a[i], b[j], acc[i][j]);
        }
        __syncthreads();
    }
#pragma unroll
    for (int i = 0; i < 4; ++i) {
        int gr = bm0 + ty * 4 + i;
#pragma unroll
        for (int j = 0; j < 4; ++j) {
            int gc = bn0 + tx * 4 + j;
            X[(size_t)gr * 320 + gc] = acc[i][j] + bp[gc];
        }
    }
}

extern "C" void kernel_launch(void* const* d_in, const int* in_sizes, int n_in,
                              void* d_out, int out_size, void* d_ws, size_t ws_size,
                              hipStream_t stream) {
    const float* geo      = (const float*)d_in[0];
    const float* sem      = (const float*)d_in[1];
    const float* w_ih0    = (const float*)d_in[2];
    const float* w_hh0    = (const float*)d_in[3];
    const float* b_ih0    = (const float*)d_in[4];
    const float* b_hh0    = (const float*)d_in[5];
    const float* w_ih1    = (const float*)d_in[6];
    const float* w_hh1    = (const float*)d_in[7];
    const float* b_ih1    = (const float*)d_in[8];
    const float* b_hh1    = (const float*)d_in[9];
    const float* w_energy = (const float*)d_in[10];
    const float* b_energy = (const float*)d_in[11];
    const float* w_proj   = (const float*)d_in[12];
    const float* b_proj   = (const float*)d_in[13];
    const float* w_op     = (const float*)d_in[14];
    const float* op_emb   = (const float*)d_in[15];

    char* p = (char*)d_ws;
    auto alloc = [&](size_t bytes) { char* q = p; p += (bytes + 255) & ~255ULL; return q; };
    float* x     = (float*)alloc((size_t)B * INDIM * 4);
    float* h0a   = (float*)alloc((size_t)B * H * 4);
    float* h0b   = (float*)alloc((size_t)B * H * 4);
    float* h1a   = (float*)alloc((size_t)B * H * 4);
    float* h1b   = (float*)alloc((size_t)B * H * 4);
    float* opp   = (float*)alloc((size_t)NOPS * 256 * 4);
    float* oppsq = (float*)alloc((size_t)NOPS * 4);
    float* hsq   = (float*)alloc((size_t)B * 4);
    int*   sel   = (int*)  alloc((size_t)B * 4);
    f16*   weh   = (f16*)  alloc((size_t)NOPS * 256 * 2);
    f16*   wel   = (f16*)  alloc((size_t)NOPS * 256 * 2);
    f16*   oph   = (f16*)  alloc((size_t)NOPS * 256 * 2);
    f16*   opl   = (f16*)  alloc((size_t)NOPS * 256 * 2);
    f16*   hh    = (f16*)  alloc((size_t)B * 256 * 2);
    f16*   hl    = (f16*)  alloc((size_t)B * 256 * 2);

    float* out    = (float*)d_out;
    float* traj   = out;
    float* scores = out + (size_t)STEPS * B;

    init_kernel<<<dim3((B * INDIM + 255) / 256), dim3(256), 0, stream>>>(geo, sem, x, h0a, h1a);
    gemm_tn<<<dim3(256 / BN, (NOPS + BM - 1) / BM), dim3(256), 0, stream>>>(
        op_emb, w_op, nullptr, opp, NOPS, 256, 256);
    // one-time fp16 hi/lo conversions of the step-invariant operands
    cvt_rows<<<dim3((NOPS + 3) / 4), dim3(256), 0, stream>>>(w_energy, NOPS, weh, wel, nullptr);
    cvt_rows<<<dim3((NOPS + 3) / 4), dim3(256), 0, stream>>>(opp, NOPS, oph, opl, oppsq);

    for (int t = 0; t < STEPS; ++t) {
        const float* h0_in = (t & 1) ? h0b : h0a;
        float*       h0_out = (t & 1) ? h0a : h0b;
        const float* h1_in = (t & 1) ? h1b : h1a;
        float*       h1_out = (t & 1) ? h1a : h1b;

        gru_fused<<<dim3(H / 64, B / 32), dim3(256), 0, stream>>>(
            x, INDIM, h0_in, w_ih0, w_hh0, b_ih0, b_hh0, h0_out);
        gru_fused<<<dim3(H / 64, B / 32), dim3(256), 0, stream>>>(
            h0_out, H, h1_in, w_ih1, w_hh1, b_ih1, b_hh1, h1_out);

        cvt_rows<<<dim3(B / 4), dim3(256), 0, stream>>>(h1_out, B, hh, hl, hsq);
        scores_mfma<<<dim3((NOPS + 63) / 64, B / 128), dim3(256), 0, stream>>>(
            hh, hl, weh, wel, oph, opl, hsq, b_energy, oppsq,
            scores + (size_t)t * B * NOPS);
        argmax_kernel<<<dim3(B), dim3(256), 0, stream>>>(
            scores + (size_t)t * B * NOPS, sel, traj + (size_t)t * B);
        proj_kernel<<<dim3(320 / BN, B / BM), dim3(256), 0, stream>>>(
            h1_out, op_emb, sel, w_proj, b_proj, x);
    }
}

// Round 3
// 3106.065 us; speedup vs baseline: 1.4191x; 1.0665x over previous
//
#include <hip/hip_runtime.h>
#include <math.h>

#define B 2048
#define H 256
#define INDIM 320
#define NOPS 1883
#define STEPS 20

typedef _Float16 f16;
typedef _Float16 f16x4 __attribute__((ext_vector_type(4)));
typedef _Float16 f16x8 __attribute__((ext_vector_type(8)));
typedef float f32x4 __attribute__((ext_vector_type(4)));

// XOR swizzle: 4 16B-slots per 64B row; bijective involution per row.
#define SWZ(r, s) ((s) ^ ((r) & 3) ^ (((r) >> 2) & 1))

#define S1 (1.0f / 1024.0f)
#define S2 (1.0f / 1048576.0f)

__device__ __forceinline__ void split3(float f, f16& c0, f16& c1, f16& c2) {
    c0 = (f16)f;
    float r1 = f - (float)c0;
    c1 = (f16)(r1 * 1024.0f);
    float r2 = r1 - (float)c1 * S1;
    c2 = (f16)(r2 * 1048576.0f);
}

// ---------------- init: x = concat(geo,sem) triple-split; zero h state ----------------
__global__ __launch_bounds__(256) void init_kernel(const float* __restrict__ geo,
                                                   const float* __restrict__ sem,
                                                   f16* __restrict__ x0, f16* __restrict__ x1,
                                                   f16* __restrict__ x2,
                                                   float* __restrict__ h0f, float* __restrict__ h1f,
                                                   f16* __restrict__ h0c0, f16* __restrict__ h0c1,
                                                   f16* __restrict__ h0c2,
                                                   f16* __restrict__ h1c0, f16* __restrict__ h1c1,
                                                   f16* __restrict__ h1c2) {
    int i = blockIdx.x * blockDim.x + threadIdx.x;
    if (i < B * INDIM) {
        int b = i / INDIM, c = i % INDIM;
        float f = (c < 256) ? geo[b * 256 + c] : sem[b * 64 + (c - 256)];
        f16 a, bb, cc;
        split3(f, a, bb, cc);
        x0[i] = a; x1[i] = bb; x2[i] = cc;
    }
    if (i < B * H) {
        h0f[i] = 0.0f; h1f[i] = 0.0f;
        h0c0[i] = (f16)0.0f; h0c1[i] = (f16)0.0f; h0c2[i] = (f16)0.0f;
        h1c0[i] = (f16)0.0f; h1c1[i] = (f16)0.0f; h1c2[i] = (f16)0.0f;
    }
}

// ---------------- generic tiled GEMM (used only for opp precompute) ----------------
#define BM 64
#define BN 64
#define BK 16
__global__ __launch_bounds__(256) void gemm_tn(const float* __restrict__ A,
                                               const float* __restrict__ Bm,
                                               const float* __restrict__ bias,
                                               float* __restrict__ C,
                                               int M, int N, int K) {
    __shared__ float As[BK][BM];
    __shared__ float Bs[BK][BN];
    int tid = threadIdx.x;
    int bm0 = blockIdx.y * BM;
    int bn0 = blockIdx.x * BN;
    int tx = tid & 15, ty = tid >> 4;
    int lr = tid >> 2;
    int lk = (tid & 3) << 2;

    float acc[4][4];
#pragma unroll
    for (int i = 0; i < 4; ++i)
#pragma unroll
        for (int j = 0; j < 4; ++j) acc[i][j] = 0.0f;

    for (int k0 = 0; k0 < K; k0 += BK) {
        {
            int gr = bm0 + lr;
            float4 v = make_float4(0.f, 0.f, 0.f, 0.f);
            if (gr < M) v = *(const float4*)(A + (size_t)gr * K + k0 + lk);
            As[lk + 0][lr] = v.x; As[lk + 1][lr] = v.y;
            As[lk + 2][lr] = v.z; As[lk + 3][lr] = v.w;
        }
        {
            int gn = bn0 + lr;
            float4 v = make_float4(0.f, 0.f, 0.f, 0.f);
            if (gn < N) v = *(const float4*)(Bm + (size_t)gn * K + k0 + lk);
            Bs[lk + 0][lr] = v.x; Bs[lk + 1][lr] = v.y;
            Bs[lk + 2][lr] = v.z; Bs[lk + 3][lr] = v.w;
        }
        __syncthreads();
#pragma unroll
        for (int k = 0; k < BK; ++k) {
            float a[4], b[4];
#pragma unroll
            for (int i = 0; i < 4; ++i) a[i] = As[k][ty * 4 + i];
#pragma unroll
            for (int j = 0; j < 4; ++j) b[j] = Bs[k][tx * 4 + j];
#pragma unroll
            for (int i = 0; i < 4; ++i)
#pragma unroll
                for (int j = 0; j < 4; ++j) acc[i][j] = fmaf(a[i], b[j], acc[i][j]);
        }
        __syncthreads();
    }
#pragma unroll
    for (int i = 0; i < 4; ++i) {
        int gr = bm0 + ty * 4 + i;
        if (gr >= M) continue;
#pragma unroll
        for (int j = 0; j < 4; ++j) {
            int gc = bn0 + tx * 4 + j;
            if (gc < N) C[(size_t)gr * N + gc] = acc[i][j] + (bias ? bias[gc] : 0.0f);
        }
    }
}

// ---------------- fp32 -> fp16 hi/lo double split (lo x1024) + optional row sumsq -----
__global__ __launch_bounds__(256) void cvt_rows(const float* __restrict__ A, int rows, int cols,
                                                f16* __restrict__ hi, f16* __restrict__ lo,
                                                float* __restrict__ sq) {
    int row = blockIdx.x * 4 + (threadIdx.x >> 6);
    int lane = threadIdx.x & 63;
    if (row >= rows) return;
    const float* src = A + (size_t)row * cols;
    float s = 0.0f;
    for (int c0 = 0; c0 < cols; c0 += 256) {
        int idx = c0 + lane * 4;
        if (idx < cols) {
            float4 v = *(const float4*)(src + idx);
            float vv[4] = {v.x, v.y, v.z, v.w};
            f16x4 h, l;
#pragma unroll
            for (int j = 0; j < 4; ++j) {
                float f = vv[j];
                f16 hv = (f16)f;
                h[j] = hv;
                l[j] = (f16)((f - (float)hv) * 1024.0f);
                s = fmaf(f, f, s);
            }
            *(f16x4*)(hi + (size_t)row * cols + idx) = h;
            *(f16x4*)(lo + (size_t)row * cols + idx) = l;
        }
    }
    if (sq) {
#pragma unroll
        for (int off = 32; off > 0; off >>= 1) s += __shfl_down(s, off);
        if (lane == 0) sq[row] = s;
    }
}

// ---------------- fp32 -> fp16 triple split ----------------
__global__ __launch_bounds__(256) void cvt3_rows(const float* __restrict__ A, int rows, int cols,
                                                 f16* __restrict__ o0, f16* __restrict__ o1,
                                                 f16* __restrict__ o2) {
    int row = blockIdx.x * 4 + (threadIdx.x >> 6);
    int lane = threadIdx.x & 63;
    if (row >= rows) return;
    const float* src = A + (size_t)row * cols;
    for (int c0 = 0; c0 < cols; c0 += 256) {
        int idx = c0 + lane * 4;
        if (idx < cols) {
            float4 v = *(const float4*)(src + idx);
            float vv[4] = {v.x, v.y, v.z, v.w};
            f16x4 a, b, c;
#pragma unroll
            for (int j = 0; j < 4; ++j) {
                f16 p, q, r;
                split3(vv[j], p, q, r);
                a[j] = p; b[j] = q; c[j] = r;
            }
            *(f16x4*)(o0 + (size_t)row * cols + idx) = a;
            *(f16x4*)(o1 + (size_t)row * cols + idx) = b;
            *(f16x4*)(o2 + (size_t)row * cols + idx) = c;
        }
    }
}

// ---------------- triple-split MFMA GRU layer ----------------
// Tile 32 batch x 32 H-cols (96 gate-cols). grid (8, 64), 4 waves.
// 6 MFMA per gate per k-chunk: a0b0 -> acc; a0b1+a1b0 -> accx; a0b2+a1b1+a2b0 -> accy.
__device__ __forceinline__ void gru_phase3(
    const f16* __restrict__ A0, const f16* __restrict__ A1, const f16* __restrict__ A2,
    const f16* __restrict__ W0, const f16* __restrict__ W1, const f16* __restrict__ W2,
    int K, int m0, int c0, int tid, int lane, int mw, int hhalf,
    f32x4* acc, f32x4* accx, f32x4* accy, f16* sA, f16* sW) {
    for (int k0 = 0; k0 < K; k0 += 32) {
        // stage A: 3 thirds x 32 rows x 4 slots = 384 float4 writes
#pragma unroll
        for (int it = 0; it < 2; ++it) {
            int flat = tid + 256 * it;
            if (flat < 384) {
                int third = flat >> 7;
                int within = flat & 127;
                int row = within >> 2, slot = within & 3;
                const f16* src = (third == 0 ? A0 : third == 1 ? A1 : A2)
                                 + (size_t)(m0 + row) * K + k0 + slot * 8;
                *(float4*)&sA[third * 1024 + row * 32 + SWZ(row, slot) * 8] = *(const float4*)src;
            }
        }
        // stage W: 3 thirds x 96 rows x 4 slots = 1152 float4 writes
#pragma unroll
        for (int third = 0; third < 3; ++third)
#pragma unroll
            for (int it = 0; it < 2; ++it) {
                int flat = tid + 256 * it;
                if (flat < 384) {
                    int row = flat >> 2, slot = flat & 3;
                    int wr = ((row >> 5) << 8) + c0 + (row & 31);
                    const f16* src = (third == 0 ? W0 : third == 1 ? W1 : W2)
                                     + (size_t)wr * K + k0 + slot * 8;
                    *(float4*)&sW[third * 3072 + row * 32 + SWZ(row, slot) * 8] = *(const float4*)src;
                }
            }
        __syncthreads();
        int ar = mw * 16 + (lane & 15);
        int asl = SWZ(ar, lane >> 4);
        f16x8 a0 = *(const f16x8*)&sA[ar * 32 + asl * 8];
        f16x8 a1 = *(const f16x8*)&sA[1024 + ar * 32 + asl * 8];
        f16x8 a2 = *(const f16x8*)&sA[2048 + ar * 32 + asl * 8];
#pragma unroll
        for (int g = 0; g < 3; ++g) {
            int br_ = g * 32 + hhalf * 16 + (lane & 15);
            int bsl = SWZ(br_, lane >> 4);
            f16x8 b0 = *(const f16x8*)&sW[br_ * 32 + bsl * 8];
            f16x8 b1 = *(const f16x8*)&sW[3072 + br_ * 32 + bsl * 8];
            f16x8 b2 = *(const f16x8*)&sW[6144 + br_ * 32 + bsl * 8];
            acc[g]  = __builtin_amdgcn_mfma_f32_16x16x32_f16(a0, b0, acc[g], 0, 0, 0);
            accx[g] = __builtin_amdgcn_mfma_f32_16x16x32_f16(a0, b1, accx[g], 0, 0, 0);
            accx[g] = __builtin_amdgcn_mfma_f32_16x16x32_f16(a1, b0, accx[g], 0, 0, 0);
            accy[g] = __builtin_amdgcn_mfma_f32_16x16x32_f16(a0, b2, accy[g], 0, 0, 0);
            accy[g] = __builtin_amdgcn_mfma_f32_16x16x32_f16(a1, b1, accy[g], 0, 0, 0);
            accy[g] = __builtin_amdgcn_mfma_f32_16x16x32_f16(a2, b0, accy[g], 0, 0, 0);
        }
        __syncthreads();
    }
}

__global__ __launch_bounds__(256) void gru_mfma3(
    const f16* __restrict__ A0, const f16* __restrict__ A1, const f16* __restrict__ A2, int K1,
    const f16* __restrict__ Wi0, const f16* __restrict__ Wi1, const f16* __restrict__ Wi2,
    const f16* __restrict__ P0, const f16* __restrict__ P1, const f16* __restrict__ P2,
    const f16* __restrict__ Wh0, const f16* __restrict__ Wh1, const f16* __restrict__ Wh2,
    const float* __restrict__ bih, const float* __restrict__ bhh,
    const float* __restrict__ Hprevf,
    float* __restrict__ Hnewf,
    f16* __restrict__ O0, f16* __restrict__ O1, f16* __restrict__ O2) {
    __shared__ f16 sA[3 * 32 * 32];
    __shared__ f16 sW[3 * 96 * 32];
    int tid = threadIdx.x;
    int lane = tid & 63;
    int wave = tid >> 6;
    int mw = wave & 1;
    int hhalf = wave >> 1;
    int c0 = blockIdx.x * 32;
    int m0 = blockIdx.y * 32;

    f32x4 acc[3], accx[3], accy[3];
#pragma unroll
    for (int g = 0; g < 3; ++g) {
        acc[g] = (f32x4){0.f, 0.f, 0.f, 0.f};
        accx[g] = (f32x4){0.f, 0.f, 0.f, 0.f};
        accy[g] = (f32x4){0.f, 0.f, 0.f, 0.f};
    }

    gru_phase3(A0, A1, A2, Wi0, Wi1, Wi2, K1, m0, c0, tid, lane, mw, hhalf,
               acc, accx, accy, sA, sW);

    float gi[3][4];
#pragma unroll
    for (int g = 0; g < 3; ++g)
#pragma unroll
        for (int r = 0; r < 4; ++r) {
            gi[g][r] = acc[g][r] + accx[g][r] * S1 + accy[g][r] * S2;
            acc[g][r] = 0.f; accx[g][r] = 0.f; accy[g][r] = 0.f;
        }

    gru_phase3(P0, P1, P2, Wh0, Wh1, Wh2, 256, m0, c0, tid, lane, mw, hhalf,
               acc, accx, accy, sA, sW);

    int c = c0 + hhalf * 16 + (lane & 15);
    float br = bih[c] + bhh[c];
    float bz = bih[256 + c] + bhh[256 + c];
    float bni = bih[512 + c];
    float bnh = bhh[512 + c];
#pragma unroll
    for (int r = 0; r < 4; ++r) {
        int row = m0 + mw * 16 + (lane >> 4) * 4 + r;
        float gh_r = acc[0][r] + accx[0][r] * S1 + accy[0][r] * S2;
        float gh_z = acc[1][r] + accx[1][r] * S1 + accy[1][r] * S2;
        float gh_n = acc[2][r] + accx[2][r] * S1 + accy[2][r] * S2;
        float rg = 1.0f / (1.0f + expf(-(gi[0][r] + gh_r + br)));
        float zg = 1.0f / (1.0f + expf(-(gi[1][r] + gh_z + bz)));
        float ng = tanhf(gi[2][r] + bni + rg * (gh_n + bnh));
        float hp = Hprevf[(size_t)row * 256 + c];
        float o = (1.0f - zg) * ng + zg * hp;
        Hnewf[(size_t)row * 256 + c] = o;
        f16 q0, q1, q2;
        split3(o, q0, q1, q2);
        O0[(size_t)row * 256 + c] = q0;
        O1[(size_t)row * 256 + c] = q1;
        O2[(size_t)row * 256 + c] = q2;
    }
}

// ---------------- MFMA split-fp16 scores (R1-validated): logits & -2*h.opp ------------
__global__ __launch_bounds__(256, 2) void scores_mfma(
    const f16* __restrict__ Ahh, const f16* __restrict__ All,
    const f16* __restrict__ W1h, const f16* __restrict__ W1l,
    const f16* __restrict__ W2h, const f16* __restrict__ W2l,
    const float* __restrict__ hsq, const float* __restrict__ be,
    const float* __restrict__ osq, float* __restrict__ out) {
    __shared__ f16 sA[2][128][32];
    __shared__ f16 sB[4][64][32];
    int tid = threadIdx.x;
    int lane = tid & 63;
    int wave = tid >> 6;
    int wm = wave >> 1;
    int wn = wave & 1;
    int n0 = blockIdx.x * 64;
    int m0 = blockIdx.y * 128;

    f32x4 acc1[4][2], acc1x[4][2], acc2[4][2], acc2x[4][2];
#pragma unroll
    for (int i = 0; i < 4; ++i)
#pragma unroll
        for (int j = 0; j < 2; ++j) {
            acc1[i][j] = (f32x4){0.f, 0.f, 0.f, 0.f};
            acc1x[i][j] = (f32x4){0.f, 0.f, 0.f, 0.f};
            acc2[i][j] = (f32x4){0.f, 0.f, 0.f, 0.f};
            acc2x[i][j] = (f32x4){0.f, 0.f, 0.f, 0.f};
        }

    int rB = tid >> 2, slB = tid & 3;
    int gn = n0 + rB;
    bool okB = gn < NOPS;

    for (int k0 = 0; k0 < 256; k0 += 32) {
#pragma unroll
        for (int it = 0; it < 4; ++it) {
            const f16* src = (it < 2) ? Ahh : All;
            int r = (tid >> 2) + ((it & 1) << 6);
            int slt = tid & 3;
            float4 v = *(const float4*)(src + (size_t)(m0 + r) * 256 + k0 + slt * 8);
            *(float4*)&sA[it >> 1][r][SWZ(r, slt) * 8] = v;
        }
#pragma unroll
        for (int it = 0; it < 4; ++it) {
            const f16* src = (it == 0) ? W1h : (it == 1) ? W1l : (it == 2) ? W2h : W2l;
            float4 v = make_float4(0.f, 0.f, 0.f, 0.f);
            if (okB) v = *(const float4*)(src + (size_t)gn * 256 + k0 + slB * 8);
            *(float4*)&sB[it][rB][SWZ(rB, slB) * 8] = v;
        }
        __syncthreads();

        f16x8 ah[4], al[4];
#pragma unroll
        for (int fm = 0; fm < 4; ++fm) {
            int r = wm * 64 + fm * 16 + (lane & 15);
            int sl = SWZ(r, lane >> 4);
            ah[fm] = *(const f16x8*)&sA[0][r][sl * 8];
            al[fm] = *(const f16x8*)&sA[1][r][sl * 8];
        }
#pragma unroll
        for (int fn = 0; fn < 2; ++fn) {
            int r = wn * 32 + fn * 16 + (lane & 15);
            int sl = SWZ(r, lane >> 4);
            f16x8 b1h = *(const f16x8*)&sB[0][r][sl * 8];
            f16x8 b1l = *(const f16x8*)&sB[1][r][sl * 8];
            f16x8 b2h = *(const f16x8*)&sB[2][r][sl * 8];
            f16x8 b2l = *(const f16x8*)&sB[3][r][sl * 8];
#pragma unroll
            for (int fm = 0; fm < 4; ++fm) {
                acc1[fm][fn]  = __builtin_amdgcn_mfma_f32_16x16x32_f16(ah[fm], b1h, acc1[fm][fn], 0, 0, 0);
                acc1x[fm][fn] = __builtin_amdgcn_mfma_f32_16x16x32_f16(al[fm], b1h, acc1x[fm][fn], 0, 0, 0);
                acc1x[fm][fn] = __builtin_amdgcn_mfma_f32_16x16x32_f16(ah[fm], b1l, acc1x[fm][fn], 0, 0, 0);
                acc2[fm][fn]  = __builtin_amdgcn_mfma_f32_16x16x32_f16(ah[fm], b2h, acc2[fm][fn], 0, 0, 0);
                acc2x[fm][fn] = __builtin_amdgcn_mfma_f32_16x16x32_f16(al[fm], b2h, acc2x[fm][fn], 0, 0, 0);
                acc2x[fm][fn] = __builtin_amdgcn_mfma_f32_16x16x32_f16(ah[fm], b2l, acc2x[fm][fn], 0, 0, 0);
            }
        }
        __syncthreads();
    }

    const float inv = 1.0f / 1024.0f;
#pragma unroll
    for (int fn = 0; fn < 2; ++fn) {
        int n = n0 + wn * 32 + fn * 16 + (lane & 15);
        if (n >= NOPS) continue;
        float bev = be[n], osv = osq[n];
#pragma unroll
        for (int fm = 0; fm < 4; ++fm) {
#pragma unroll
            for (int r = 0; r < 4; ++r) {
                int m = m0 + wm * 64 + fm * 16 + (lane >> 4) * 4 + r;
                float dot1 = acc1[fm][fn][r] + acc1x[fm][fn][r] * inv;
                float dot2 = acc2[fm][fn][r] + acc2x[fm][fn][r] * inv;
                float logit = dot1 + bev;
                float d2 = hsq[m] + osv - 2.0f * dot2;
                out[(size_t)m * NOPS + n] = logit - 0.5f * sqrtf(fmaxf(d2, 0.0f));
            }
        }
    }
}

// ---------------- per-row argmax (first-index tie-break) ----------------
__global__ __launch_bounds__(256) void argmax_kernel(const float* __restrict__ scores,
                                                     int* __restrict__ sel,
                                                     float* __restrict__ traj) {
    int b = blockIdx.x;
    const float* row = scores + (size_t)b * NOPS;
    float bv = -INFINITY; int bi = 0x7fffffff;
    for (int n = threadIdx.x; n < NOPS; n += 256) {
        float v = row[n];
        if (v > bv) { bv = v; bi = n; }
    }
    __shared__ float sv[256];
    __shared__ int si[256];
    sv[threadIdx.x] = bv; si[threadIdx.x] = bi;
    __syncthreads();
    for (int s = 128; s > 0; s >>= 1) {
        if (threadIdx.x < s) {
            float ov = sv[threadIdx.x + s]; int oi = si[threadIdx.x + s];
            if (ov > sv[threadIdx.x] || (ov == sv[threadIdx.x] && oi < si[threadIdx.x])) {
                sv[threadIdx.x] = ov; si[threadIdx.x] = oi;
            }
        }
        __syncthreads();
    }
    if (threadIdx.x == 0) { sel[b] = si[0]; traj[b] = (float)si[0]; }
}

// ---------------- triple-split MFMA proj: x = [h_top, emb[sel]] @ Wp^T + bp -----------
// Tile 32(M) x 64(N), grid (5, 64), 4 waves (wave: mw = w&1, n-half = w>>1).
__global__ __launch_bounds__(256) void proj_mfma3(
    const f16* __restrict__ H0, const f16* __restrict__ H1, const f16* __restrict__ H2,
    const f16* __restrict__ E0, const f16* __restrict__ E1, const f16* __restrict__ E2,
    const int* __restrict__ sel,
    const f16* __restrict__ W0, const f16* __restrict__ W1, const f16* __restrict__ W2,
    const float* __restrict__ bp,
    f16* __restrict__ X0, f16* __restrict__ X1, f16* __restrict__ X2) {
    __shared__ f16 sA[3 * 32 * 32];
    __shared__ f16 sB[3 * 64 * 32];
    int tid = threadIdx.x;
    int lane = tid & 63;
    int wave = tid >> 6;
    int mw = wave & 1;
    int nh = wave >> 1;
    int n0 = blockIdx.x * 64;
    int m0 = blockIdx.y * 32;

    f32x4 acc[2], accx[2], accy[2];
#pragma unroll
    for (int j = 0; j < 2; ++j) {
        acc[j] = (f32x4){0.f, 0.f, 0.f, 0.f};
        accx[j] = (f32x4){0.f, 0.f, 0.f, 0.f};
        accy[j] = (f32x4){0.f, 0.f, 0.f, 0.f};
    }

    for (int k0 = 0; k0 < 512; k0 += 32) {
        // stage A: 3 thirds x 32 rows x 4 slots
#pragma unroll
        for (int it = 0; it < 2; ++it) {
            int flat = tid + 256 * it;
            if (flat < 384) {
                int third = flat >> 7;
                int within = flat & 127;
                int row = within >> 2, slot = within & 3;
                int gr = m0 + row;
                const f16* src;
                if (k0 < 256) {
                    const f16* base = (third == 0 ? H0 : third == 1 ? H1 : H2);
                    src = base + (size_t)gr * 256 + k0 + slot * 8;
                } else {
                    const f16* base = (third == 0 ? E0 : third == 1 ? E1 : E2);
                    src = base + (size_t)sel[gr] * 256 + (k0 - 256) + slot * 8;
                }
                *(float4*)&sA[third * 1024 + row * 32 + SWZ(row, slot) * 8] = *(const float4*)src;
            }
        }
        // stage B: 3 thirds x 64 rows x 4 slots = 768 writes (exactly 3 full passes)
#pragma unroll
        for (int third = 0; third < 3; ++third) {
            int row = tid >> 2, slot = tid & 3;
            const f16* src = (third == 0 ? W0 : third == 1 ? W1 : W2)
                             + (size_t)(n0 + row) * 512 + k0 + slot * 8;
            *(float4*)&sB[third * 2048 + row * 32 + SWZ(row, slot) * 8] = *(const float4*)src;
        }
        __syncthreads();
        int ar = mw * 16 + (lane & 15);
        int asl = SWZ(ar, lane >> 4);
        f16x8 a0 = *(const f16x8*)&sA[ar * 32 + asl * 8];
        f16x8 a1 = *(const f16x8*)&sA[1024 + ar * 32 + asl * 8];
        f16x8 a2 = *(const f16x8*)&sA[2048 + ar * 32 + asl * 8];
#pragma unroll
        for (int j = 0; j < 2; ++j) {
            int brr = (nh * 2 + j) * 16 + (lane & 15);
            int bsl = SWZ(brr, lane >> 4);
            f16x8 b0 = *(const f16x8*)&sB[brr * 32 + bsl * 8];
            f16x8 b1 = *(const f16x8*)&sB[2048 + brr * 32 + bsl * 8];
            f16x8 b2 = *(const f16x8*)&sB[4096 + brr * 32 + bsl * 8];
            acc[j]  = __builtin_amdgcn_mfma_f32_16x16x32_f16(a0, b0, acc[j], 0, 0, 0);
            accx[j] = __builtin_amdgcn_mfma_f32_16x16x32_f16(a0, b1, accx[j], 0, 0, 0);
            accx[j] = __builtin_amdgcn_mfma_f32_16x16x32_f16(a1, b0, accx[j], 0, 0, 0);
            accy[j] = __builtin_amdgcn_mfma_f32_16x16x32_f16(a0, b2, accy[j], 0, 0, 0);
            accy[j] = __builtin_amdgcn_mfma_f32_16x16x32_f16(a1, b1, accy[j], 0, 0, 0);
            accy[j] = __builtin_amdgcn_mfma_f32_16x16x32_f16(a2, b0, accy[j], 0, 0, 0);
        }
        __syncthreads();
    }

#pragma unroll
    for (int j = 0; j < 2; ++j) {
        int n = n0 + (nh * 2 + j) * 16 + (lane & 15);
        float bv = bp[n];
#pragma unroll
        for (int r = 0; r < 4; ++r) {
            int m = m0 + mw * 16 + (lane >> 4) * 4 + r;
            float o = acc[j][r] + accx[j][r] * S1 + accy[j][r] * S2 + bv;
            f16 q0, q1, q2;
            split3(o, q0, q1, q2);
            X0[(size_t)m * 320 + n] = q0;
            X1[(size_t)m * 320 + n] = q1;
            X2[(size_t)m * 320 + n] = q2;
        }
    }
}

extern "C" void kernel_launch(void* const* d_in, const int* in_sizes, int n_in,
                              void* d_out, int out_size, void* d_ws, size_t ws_size,
                              hipStream_t stream) {
    const float* geo      = (const float*)d_in[0];
    const float* sem      = (const float*)d_in[1];
    const float* w_ih0    = (const float*)d_in[2];
    const float* w_hh0    = (const float*)d_in[3];
    const float* b_ih0    = (const float*)d_in[4];
    const float* b_hh0    = (const float*)d_in[5];
    const float* w_ih1    = (const float*)d_in[6];
    const float* w_hh1    = (const float*)d_in[7];
    const float* b_ih1    = (const float*)d_in[8];
    const float* b_hh1    = (const float*)d_in[9];
    const float* w_energy = (const float*)d_in[10];
    const float* b_energy = (const float*)d_in[11];
    const float* w_proj   = (const float*)d_in[12];
    const float* b_proj   = (const float*)d_in[13];
    const float* w_op     = (const float*)d_in[14];
    const float* op_emb   = (const float*)d_in[15];

    char* p = (char*)d_ws;
    auto alloc = [&](size_t bytes) { char* q = p; p += (bytes + 255) & ~255ULL; return q; };
    float* opp   = (float*)alloc((size_t)NOPS * 256 * 4);
    float* oppsq = (float*)alloc((size_t)NOPS * 4);
    float* hsq   = (float*)alloc((size_t)B * 4);
    int*   sel   = (int*)  alloc((size_t)B * 4);
    float *h0f[2], *h1f[2];
    f16 *h0c0[2], *h0c1[2], *h0c2[2], *h1c0[2], *h1c1[2], *h1c2[2];
    for (int i = 0; i < 2; ++i) {
        h0f[i]  = (float*)alloc((size_t)B * H * 4);
        h1f[i]  = (float*)alloc((size_t)B * H * 4);
        h0c0[i] = (f16*)alloc((size_t)B * H * 2);
        h0c1[i] = (f16*)alloc((size_t)B * H * 2);
        h0c2[i] = (f16*)alloc((size_t)B * H * 2);
        h1c0[i] = (f16*)alloc((size_t)B * H * 2);
        h1c1[i] = (f16*)alloc((size_t)B * H * 2);
        h1c2[i] = (f16*)alloc((size_t)B * H * 2);
    }
    f16* x0 = (f16*)alloc((size_t)B * INDIM * 2);
    f16* x1 = (f16*)alloc((size_t)B * INDIM * 2);
    f16* x2 = (f16*)alloc((size_t)B * INDIM * 2);
    f16 *wi0[3], *wh0[3], *wi1[3], *wh1[3], *wp[3], *emb[3];
    for (int i = 0; i < 3; ++i) {
        wi0[i] = (f16*)alloc((size_t)768 * 320 * 2);
        wh0[i] = (f16*)alloc((size_t)768 * 256 * 2);
        wi1[i] = (f16*)alloc((size_t)768 * 256 * 2);
        wh1[i] = (f16*)alloc((size_t)768 * 256 * 2);
        wp[i]  = (f16*)alloc((size_t)320 * 512 * 2);
        emb[i] = (f16*)alloc((size_t)NOPS * 256 * 2);
    }
    f16* weh = (f16*)alloc((size_t)NOPS * 256 * 2);
    f16* wel = (f16*)alloc((size_t)NOPS * 256 * 2);
    f16* oph = (f16*)alloc((size_t)NOPS * 256 * 2);
    f16* opl = (f16*)alloc((size_t)NOPS * 256 * 2);
    f16* hs0 = (f16*)alloc((size_t)B * 256 * 2);
    f16* hs1 = (f16*)alloc((size_t)B * 256 * 2);

    float* out    = (float*)d_out;
    float* traj   = out;
    float* scores = out + (size_t)STEPS * B;

    init_kernel<<<dim3((B * INDIM + 255) / 256), dim3(256), 0, stream>>>(
        geo, sem, x0, x1, x2, h0f[0], h1f[0],
        h0c0[0], h0c1[0], h0c2[0], h1c0[0], h1c1[0], h1c2[0]);
    gemm_tn<<<dim3(256 / BN, (NOPS + BM - 1) / BM), dim3(256), 0, stream>>>(
        op_emb, w_op, nullptr, opp, NOPS, 256, 256);
    // one-time splits: triple for recurrence-path operands, double for scores-path
    cvt3_rows<<<dim3(192), dim3(256), 0, stream>>>(w_ih0, 768, 320, wi0[0], wi0[1], wi0[2]);
    cvt3_rows<<<dim3(192), dim3(256), 0, stream>>>(w_hh0, 768, 256, wh0[0], wh0[1], wh0[2]);
    cvt3_rows<<<dim3(192), dim3(256), 0, stream>>>(w_ih1, 768, 256, wi1[0], wi1[1], wi1[2]);
    cvt3_rows<<<dim3(192), dim3(256), 0, stream>>>(w_hh1, 768, 256, wh1[0], wh1[1], wh1[2]);
    cvt3_rows<<<dim3(80), dim3(256), 0, stream>>>(w_proj, 320, 512, wp[0], wp[1], wp[2]);
    cvt3_rows<<<dim3((NOPS + 3) / 4), dim3(256), 0, stream>>>(op_emb, NOPS, 256, emb[0], emb[1], emb[2]);
    cvt_rows<<<dim3((NOPS + 3) / 4), dim3(256), 0, stream>>>(w_energy, NOPS, 256, weh, wel, nullptr);
    cvt_rows<<<dim3((NOPS + 3) / 4), dim3(256), 0, stream>>>(opp, NOPS, 256, oph, opl, oppsq);

    for (int t = 0; t < STEPS; ++t) {
        int pi = t & 1, po = pi ^ 1;

        gru_mfma3<<<dim3(H / 32, B / 32), dim3(256), 0, stream>>>(
            x0, x1, x2, INDIM, wi0[0], wi0[1], wi0[2],
            h0c0[pi], h0c1[pi], h0c2[pi], wh0[0], wh0[1], wh0[2],
            b_ih0, b_hh0, h0f[pi], h0f[po], h0c0[po], h0c1[po], h0c2[po]);
        gru_mfma3<<<dim3(H / 32, B / 32), dim3(256), 0, stream>>>(
            h0c0[po], h0c1[po], h0c2[po], 256, wi1[0], wi1[1], wi1[2],
            h1c0[pi], h1c1[pi], h1c2[pi], wh1[0], wh1[1], wh1[2],
            b_ih1, b_hh1, h1f[pi], h1f[po], h1c0[po], h1c1[po], h1c2[po]);

        // R1-validated scores path: hi/lo + hsq derived from fp32 h
        cvt_rows<<<dim3(B / 4), dim3(256), 0, stream>>>(h1f[po], B, 256, hs0, hs1, hsq);
        scores_mfma<<<dim3((NOPS + 63) / 64, B / 128), dim3(256), 0, stream>>>(
            hs0, hs1, weh, wel, oph, opl, hsq, b_energy, oppsq,
            scores + (size_t)t * B * NOPS);
        argmax_kernel<<<dim3(B), dim3(256), 0, stream>>>(
            scores + (size_t)t * B * NOPS, sel, traj + (size_t)t * B);
        proj_mfma3<<<dim3(320 / 64, B / 32), dim3(256), 0, stream>>>(
            h1c0[po], h1c1[po], h1c2[po], emb[0], emb[1], emb[2], sel,
            wp[0], wp[1], wp[2], b_proj, x0, x1, x2);
    }
}